// Round 10
// baseline (110.503 us; speedup 1.0000x reference)
//
#include <hip/hip_runtime.h>

#define DIM 64
#define NVOX (DIM * DIM * DIM)
#define EPF 53248          // boundary edges per field

// ---------------------------------------------------------------------------
// Lock-free union-find (ECL-CC style), works on global OR LDS int arrays.
// Invariant: every stored parent is a strictly-smaller-index ancestor ->
// stale (non-coherent L1) reads still see valid ancestors; atomicCAS is the
// coherent ground truth; failed CAS returns a strictly smaller value ->
// guaranteed termination.
// ---------------------------------------------------------------------------
__device__ __forceinline__ int find_root_link(int* L, int v) {
    for (;;) {
        int p = L[v];
        if (p == v) return v;
        int gp = L[p];
        if (gp == p) return p;
        L[v] = gp;   // path-halving: writes an ancestor, races benign
        v = gp;
    }
}

__device__ __forceinline__ void unite(int* L, int a, int b) {
    int ra = find_root_link(L, a);
    int rb = find_root_link(L, b);
    while (ra != rb) {
        if (ra > rb) { int t = ra; ra = rb; rb = t; }
        int old = atomicCAS(&L[rb], rb, ra);
        if (old == rb) break;            // hooked rb -> ra
        rb = find_root_link(L, old);     // old coherent, strictly < rb
        ra = find_root_link(L, ra);
    }
}

// read-only chase (no writes; valid ancestor even under concurrent unites)
__device__ __forceinline__ int chase(const int* __restrict__ L, int p) {
    int q = L[p];
    while (q != p) { p = q; q = L[p]; }
    return p;
}

// ---------------------------------------------------------------------------
// Phase 1: per-tile CCL in LDS. Tile 16x16x8 = 2048 voxels, 256 threads,
// grid (128 tiles, 2 fields). R10: float4 input loads + int4 label stores
// (16B/lane -> 4x fewer VMEM instructions; bytes unchanged).
// Writes global label = global index of tile-local root (monotone map keeps
// parent <= child globally). Block (0,0) also zeroes d_out (ordered before
// finalize's atomics by the dispatch boundary).
// ---------------------------------------------------------------------------
__global__ void local_ccl(const float* __restrict__ pred,
                          const float* __restrict__ lab,
                          int* __restrict__ LP, int* __restrict__ LL,
                          float* __restrict__ out) {
    __shared__ int s_lab[2048];
    int t = threadIdx.x;
    if (blockIdx.x == 0 && blockIdx.y == 0 && t == 0) *out = 0.0f;
    int b = blockIdx.x;                         // 128 tiles: 4 x 4 x 8
    int tx = b & 3, ty = (b >> 2) & 3, tz = b >> 4;
    int X0 = tx << 4, Y0 = ty << 4, Z0 = tz << 3;

    const float* src = blockIdx.y ? lab : pred;
    int* Lg = blockIdx.y ? LL : LP;

    int vb[2];
#pragma unroll
    for (int j = 0; j < 2; ++j) {
        int q = t + (j << 8);                   // float4 slot 0..511
        int r = q >> 2;                         // row 0..127: ly = r&15, lz = r>>4
        int lxq = (q & 3) << 2;                 // x offset within row
        int v = ((Z0 + (r >> 4)) << 12) | ((Y0 + (r & 15)) << 6) | (X0 + lxq);
        vb[j] = v;
        float4 p = *(const float4*)(src + v);   // 16B coalesced
        int l = (r << 4) | lxq;
        s_lab[l]     = (p.x > 0.0f) ? l     : -1;
        s_lab[l + 1] = (p.y > 0.0f) ? l + 1 : -1;
        s_lab[l + 2] = (p.z > 0.0f) ? l + 2 : -1;
        s_lab[l + 3] = (p.w > 0.0f) ? l + 3 : -1;
    }
    __syncthreads();

#pragma unroll
    for (int i = 0; i < 8; ++i) {
        int l = t + (i << 8);
        if (s_lab[l] < 0) continue;
        int lx = l & 15, ly = (l >> 4) & 15, lz = l >> 8;
        if (lx < 15 && s_lab[l + 1]   >= 0) unite(s_lab, l, l + 1);
        if (ly < 15 && s_lab[l + 16]  >= 0) unite(s_lab, l, l + 16);
        if (lz < 7  && s_lab[l + 256] >= 0) unite(s_lab, l, l + 256);
    }
    __syncthreads();

#pragma unroll
    for (int j = 0; j < 2; ++j) {
        int q = t + (j << 8);
        int r = q >> 2;
        int lxq = (q & 3) << 2;
        int l = (r << 4) | lxq;
        int g[4];
#pragma unroll
        for (int k = 0; k < 4; ++k) {
            int p = s_lab[l + k];
            if (p >= 0) {
                while (s_lab[p] != p) p = s_lab[p];   // read-only chase
                p = ((Z0 + (p >> 8)) << 12) | ((Y0 + ((p >> 4) & 15)) << 6)
                  | (X0 + (p & 15));                  // monotone: p <= v
            }
            g[k] = p;
        }
        *(int4*)(Lg + vb[j]) = *(int4*)g;             // 16B coalesced
    }
}

// ---------------------------------------------------------------------------
// Phase 2: compact cross-tile edge list, one thread per geometric edge,
// both fields per thread. Dedupe on the RAW tile-component pair BEFORE
// chasing (kills the dependent chase for run-duplicate lanes), then a
// second dedupe on final roots before unite. Raw labels may be mid-halving
// values; any stored value is a valid ancestor, so a missed dedupe is only
// redundancy, never an error.
// ---------------------------------------------------------------------------
__global__ void boundary_link(int* __restrict__ LP, int* __restrict__ LL) {
    int r = blockIdx.x * blockDim.x + threadIdx.x;   // 0..EPF-1
    int v, n;
    if (r < 12288) {                             // x-faces: planes 15,31,47
        int plane = 15 + ((r >> 12) << 4);
        int ij = r & 4095;                       // y = ij&63 (lane-consecutive), z = ij>>6
        v = ((ij >> 6) << 12) | ((ij & 63) << 6) | plane;
        n = v + 1;
    } else if (r < 24576) {                      // y-faces: planes 15,31,47
        int r2 = r - 12288;
        int plane = 15 + ((r2 >> 12) << 4);
        int ij = r2 & 4095;                      // x = ij&63, z = ij>>6
        v = ((ij >> 6) << 12) | (plane << 6) | (ij & 63);
        n = v + 64;
    } else {                                     // z-faces: planes 7..55
        int r3 = r - 24576;
        int plane = 7 + ((r3 >> 12) << 3);
        int ij = r3 & 4095;                      // x = ij&63, y = ij>>6
        v = (plane << 12) | ((ij >> 6) << 6) | (ij & 63);
        n = v + 4096;
    }

    int lane = threadIdx.x & 63;

    int pa = LP[v], pb = LP[n];
    int la = LL[v], lb = LL[n];
    bool doP = (pa >= 0) & (pb >= 0);
    bool doL = (la >= 0) & (lb >= 0);

    // raw-pair dedupe (kills the chase for run-duplicates)
    int xpa = __shfl_up(pa, 1, 64), xpb = __shfl_up(pb, 1, 64);
    int xla = __shfl_up(la, 1, 64), xlb = __shfl_up(lb, 1, 64);
    if (lane && xpa == pa && xpb == pb) doP = false;
    if (lane && xla == la && xlb == lb) doL = false;

    int rp0 = -1, rp1 = -1, rl0 = -1, rl1 = -1;
    if (doP) {
        int u0 = chase(LP, pa), u1 = chase(LP, pb);
        rp0 = min(u0, u1); rp1 = max(u0, u1);
    }
    if (doL) {
        int u0 = chase(LL, la), u1 = chase(LL, lb);
        rl0 = min(u0, u1); rl1 = max(u0, u1);
    }

    // root-pair dedupe (different raw pairs may share final roots)
    int qp0 = __shfl_up(rp0, 1, 64), qp1 = __shfl_up(rp1, 1, 64);
    int ql0 = __shfl_up(rl0, 1, 64), ql1 = __shfl_up(rl1, 1, 64);
    bool dupP = lane && (qp0 == rp0) && (qp1 == rp1);
    bool dupL = lane && (ql0 == rl0) && (ql1 == rl1);

    if (rp0 >= 0 && rp0 != rp1 && !dupP) unite(LP, rp0, rp1);
    if (rl0 >= 0 && rl0 != rl1 && !dupL) unite(LL, rl0, rl1);
}

// ---------------------------------------------------------------------------
// 27-bit 3x3x3 mask connectivity via branch-free separable dilation.
// Bit index = z*9 + y*3 + x.
// ---------------------------------------------------------------------------
#define MX_L 0x6DB6DB6u   // result x in {1,2}
#define MX_R 0x36DB6DBu   // result x in {0,1}
#define MY_L 0x7E3F1F8u   // result y in {1,2}
#define MY_R 0x0FC7E3Fu   // result y in {0,1}
#define M27  0x7FFFFFFu

__device__ __forceinline__ unsigned dil26(unsigned m) {
    m |= ((m << 1) & MX_L) | ((m >> 1) & MX_R);
    m |= ((m << 3) & MY_L) | ((m >> 3) & MY_R);
    m |= ((m << 9) & M27)  | (m >> 9);
    return m;
}
__device__ __forceinline__ unsigned dil18(unsigned m) {
    unsigned ax = m | ((m << 1) & MX_L) | ((m >> 1) & MX_R);    // Dx
    unsigned ay = m | ((m << 3) & MY_L) | ((m >> 3) & MY_R);    // Dy
    unsigned dxy = ax | ((ax << 3) & MY_L) | ((ax >> 3) & MY_R);      // DyDx
    unsigned dxz = ax | ((ax << 9) & M27)  | (ax >> 9);               // DzDx
    unsigned dyz = ay | ((ay << 9) & M27)  | (ay >> 9);               // DzDy
    return dxy | dxz | dyz;   // all offsets with >=1 zero component
}

__device__ __forceinline__ bool single18(unsigned m) {
    if (!m) return false;
    unsigned c = m & (~m + 1u);
    for (;;) {
        unsigned n = dil18(c) & m;
        if (n == m) return true;
        if (n == c) return false;
        c = n;
    }
}
__device__ __forceinline__ bool single26(unsigned m) {
    if (!m) return false;
    unsigned c = m & (~m + 1u);
    for (;;) {
        unsigned n = dil26(c) & m;
        if (n == m) return true;
        if (n == c) return false;
        c = n;
    }
}

// ---------------------------------------------------------------------------
// Phase 3: non-simple maps + weighted BCE + mean. Region 8x8x8 per block
// (512 blocks, 2 voxels/thread), halo 10x10x10 per field. Halo loads are
// batched (independent loads issued, then dependent chases). Halo layout:
// i = hz*100 + hy*10 + hx; window corner of (lx,ly,lz) = base; center =
// base + 111.
// ---------------------------------------------------------------------------
#define HV 1000   // 10*10*10

__global__ void finalize_kernel(const float* __restrict__ pred,
                                const float* __restrict__ lab,
                                const int* __restrict__ LP,
                                const int* __restrict__ LL,
                                float* __restrict__ out) {
    __shared__ int sP[HV], sL[HV];
    __shared__ float s_part[4];
    int t = threadIdx.x;
    int b = blockIdx.x;                          // 8 x 8 x 8 regions
    int rx = b & 7, ry = (b >> 3) & 7, rz = b >> 6;
    int x0 = rx << 3, y0 = ry << 3, z0 = rz << 3;

    // batched halo load: issue all independent loads first, then chase
    int pv[4], lv[4];
#pragma unroll
    for (int j = 0; j < 4; ++j) {
        int i = t + (j << 8);
        if (i < HV) {
            int hx = i % 10, rr = i / 10, hy = rr % 10, hz = rr / 10;
            int gx = x0 + hx - 1; gx = gx < 0 ? 0 : (gx > 63 ? 63 : gx);
            int gy = y0 + hy - 1; gy = gy < 0 ? 0 : (gy > 63 ? 63 : gy);
            int gz = z0 + hz - 1; gz = gz < 0 ? 0 : (gz > 63 ? 63 : gz);
            int gv = (gz << 12) | (gy << 6) | gx;
            pv[j] = LP[gv];
            lv[j] = LL[gv];
        }
    }
#pragma unroll
    for (int j = 0; j < 4; ++j) {
        int i = t + (j << 8);
        if (i < HV) {
            int p = pv[j];
            if (p >= 0) p = chase(LP, p);
            sP[i] = p;
            p = lv[j];
            if (p >= 0) p = chase(LL, p);
            sL[i] = p;
        }
    }
    __syncthreads();

    float acc = 0.0f;
#pragma unroll
    for (int j = 0; j < 2; ++j) {
        int l = t + (j << 8);                    // region 8x8x8: 512 voxels
        int lx = l & 7, ly = (l >> 3) & 7, lz = l >> 6;
        int x = x0 | lx, y = y0 | ly, z = z0 | lz;
        int v = (z << 12) | (y << 6) | x;
        int base = lz * 100 + ly * 10 + lx;      // (-1,-1,-1) corner

        bool nsP = false, nsL = false;
        {
            int c = sP[base + 111];              // center
            if (c >= 0) {
                unsigned m1 = 0, m2 = 0; int k = 0;
#pragma unroll
                for (int kz = 0; kz < 3; ++kz)
#pragma unroll
                    for (int ky = 0; ky < 3; ++ky)
#pragma unroll
                        for (int kx = 0; kx < 3; ++kx, ++k) {
                            int w = sP[base + kz * 100 + ky * 10 + kx];
                            m1 |= (unsigned)(w != c) << k;
                            m2 |= (unsigned)(w == c) << k;
                        }
                m2 &= ~(1u << 13);               // drop center
                nsP = !(single18(m1) && single26(m2));
            }
        }
        {
            int c = sL[base + 111];
            if (c >= 0) {
                unsigned m1 = 0, m2 = 0; int k = 0;
#pragma unroll
                for (int kz = 0; kz < 3; ++kz)
#pragma unroll
                    for (int ky = 0; ky < 3; ++ky)
#pragma unroll
                        for (int kx = 0; kx < 3; ++kx, ++k) {
                            int w = sL[base + kz * 100 + ky * 10 + kx];
                            m1 |= (unsigned)(w != c) << k;
                            m2 |= (unsigned)(w == c) << k;
                        }
                m2 &= ~(1u << 13);
                nsL = !(single18(m1) && single26(m2));
            }
        }

        float p = pred[v], lvf = lab[v];
        float cost = fmaxf(p, 0.0f) - p * lvf + log1pf(__expf(-fabsf(p)));
        acc += ((nsP || nsL) ? 5.0f : 1.0f) * cost;
    }

#pragma unroll
    for (int off = 32; off > 0; off >>= 1)
        acc += __shfl_down(acc, off, 64);
    if ((t & 63) == 0) s_part[t >> 6] = acc;
    __syncthreads();
    if (t == 0) {
        float s = s_part[0] + s_part[1] + s_part[2] + s_part[3];
        atomicAdd(out, s * (1.0f / (float)NVOX));
    }
}

extern "C" void kernel_launch(void* const* d_in, const int* in_sizes, int n_in,
                              void* d_out, int out_size, void* d_ws, size_t ws_size,
                              hipStream_t stream) {
    const float* pred = (const float*)d_in[0];   // 'prediction'
    const float* lab  = (const float*)d_in[1];   // 'label'
    float* out = (float*)d_out;

    int* LP = (int*)d_ws;          // NVOX ints
    int* LL = LP + NVOX;           // NVOX ints  (2 MiB total)

    hipLaunchKernelGGL(local_ccl, dim3(128, 2), dim3(256), 0, stream,
                       pred, lab, LP, LL, out);
    hipLaunchKernelGGL(boundary_link, dim3(EPF / 256), dim3(256), 0, stream,
                       LP, LL);
    hipLaunchKernelGGL(finalize_kernel, dim3(512), dim3(256), 0, stream,
                       pred, lab, LP, LL, out);
}

// Round 11
// 110.009 us; speedup vs baseline: 1.0045x; 1.0045x over previous
//
#include <hip/hip_runtime.h>

#define DIM 64
#define NVOX (DIM * DIM * DIM)
#define EPF 53248          // boundary edges per field

// ---------------------------------------------------------------------------
// Lock-free union-find (ECL-CC style), works on global OR LDS int arrays.
// Invariant: every stored parent is a strictly-smaller-index ancestor ->
// stale (non-coherent L1) reads still see valid ancestors; atomicCAS is the
// coherent ground truth; failed CAS returns a strictly smaller value ->
// guaranteed termination.
// ---------------------------------------------------------------------------
__device__ __forceinline__ int find_root_link(int* L, int v) {
    for (;;) {
        int p = L[v];
        if (p == v) return v;
        int gp = L[p];
        if (gp == p) return p;
        L[v] = gp;   // path-halving: writes an ancestor, races benign
        v = gp;
    }
}

__device__ __forceinline__ void unite(int* L, int a, int b) {
    int ra = find_root_link(L, a);
    int rb = find_root_link(L, b);
    while (ra != rb) {
        if (ra > rb) { int t = ra; ra = rb; rb = t; }
        int old = atomicCAS(&L[rb], rb, ra);
        if (old == rb) break;            // hooked rb -> ra
        rb = find_root_link(L, old);     // old coherent, strictly < rb
        ra = find_root_link(L, ra);
    }
}

// lockstep dual chase: both chains advance each iteration -> two independent
// loads per latency instead of two sequential dependent chains. Re-loading a
// settled root is idempotent (L[r]==r), so no per-chain guard is needed.
__device__ __forceinline__ void chase2(const int* __restrict__ L,
                                       int& a, int& b) {
    for (;;) {
        int qa = L[a];
        int qb = L[b];
        if (qa == a && qb == b) return;
        a = qa; b = qb;
    }
}

// ---------------------------------------------------------------------------
// Phase 1: per-tile CCL in LDS. Tile 16x16x8 = 2048 voxels, 256 threads,
// grid (128 tiles, 2 fields). float4 input loads + int4 label stores.
// Writes global label = global index of tile-local root (monotone map keeps
// parent <= child globally). Block (0,0) also zeroes d_out (ordered before
// finalize's atomics by the dispatch boundary).
// ---------------------------------------------------------------------------
__global__ void local_ccl(const float* __restrict__ pred,
                          const float* __restrict__ lab,
                          int* __restrict__ LP, int* __restrict__ LL,
                          float* __restrict__ out) {
    __shared__ int s_lab[2048];
    int t = threadIdx.x;
    if (blockIdx.x == 0 && blockIdx.y == 0 && t == 0) *out = 0.0f;
    int b = blockIdx.x;                         // 128 tiles: 4 x 4 x 8
    int tx = b & 3, ty = (b >> 2) & 3, tz = b >> 4;
    int X0 = tx << 4, Y0 = ty << 4, Z0 = tz << 3;

    const float* src = blockIdx.y ? lab : pred;
    int* Lg = blockIdx.y ? LL : LP;

    int vb[2];
#pragma unroll
    for (int j = 0; j < 2; ++j) {
        int q = t + (j << 8);                   // float4 slot 0..511
        int r = q >> 2;                         // row 0..127: ly = r&15, lz = r>>4
        int lxq = (q & 3) << 2;                 // x offset within row
        int v = ((Z0 + (r >> 4)) << 12) | ((Y0 + (r & 15)) << 6) | (X0 + lxq);
        vb[j] = v;
        float4 p = *(const float4*)(src + v);   // 16B coalesced
        int l = (r << 4) | lxq;
        s_lab[l]     = (p.x > 0.0f) ? l     : -1;
        s_lab[l + 1] = (p.y > 0.0f) ? l + 1 : -1;
        s_lab[l + 2] = (p.z > 0.0f) ? l + 2 : -1;
        s_lab[l + 3] = (p.w > 0.0f) ? l + 3 : -1;
    }
    __syncthreads();

#pragma unroll
    for (int i = 0; i < 8; ++i) {
        int l = t + (i << 8);
        if (s_lab[l] < 0) continue;
        int lx = l & 15, ly = (l >> 4) & 15, lz = l >> 8;
        if (lx < 15 && s_lab[l + 1]   >= 0) unite(s_lab, l, l + 1);
        if (ly < 15 && s_lab[l + 16]  >= 0) unite(s_lab, l, l + 16);
        if (lz < 7  && s_lab[l + 256] >= 0) unite(s_lab, l, l + 256);
    }
    __syncthreads();

#pragma unroll
    for (int j = 0; j < 2; ++j) {
        int q = t + (j << 8);
        int r = q >> 2;
        int lxq = (q & 3) << 2;
        int l = (r << 4) | lxq;
        int g[4];
#pragma unroll
        for (int k = 0; k < 4; ++k) {
            int p = s_lab[l + k];
            if (p >= 0) {
                while (s_lab[p] != p) p = s_lab[p];   // read-only chase
                p = ((Z0 + (p >> 8)) << 12) | ((Y0 + ((p >> 4) & 15)) << 6)
                  | (X0 + (p & 15));                  // monotone: p <= v
            }
            g[k] = p;
        }
        *(int4*)(Lg + vb[j]) = *(int4*)g;             // 16B coalesced
    }
}

// ---------------------------------------------------------------------------
// Phase 2: compact cross-tile edge list, one thread per geometric edge,
// both fields per thread. Dedupe on the RAW tile-component pair BEFORE
// chasing, then a second dedupe on final roots before unite. Chases use
// lockstep chase2 (halved dependent-chain length).
// ---------------------------------------------------------------------------
__global__ void boundary_link(int* __restrict__ LP, int* __restrict__ LL) {
    int r = blockIdx.x * blockDim.x + threadIdx.x;   // 0..EPF-1
    int v, n;
    if (r < 12288) {                             // x-faces: planes 15,31,47
        int plane = 15 + ((r >> 12) << 4);
        int ij = r & 4095;                       // y = ij&63 (lane-consecutive), z = ij>>6
        v = ((ij >> 6) << 12) | ((ij & 63) << 6) | plane;
        n = v + 1;
    } else if (r < 24576) {                      // y-faces: planes 15,31,47
        int r2 = r - 12288;
        int plane = 15 + ((r2 >> 12) << 4);
        int ij = r2 & 4095;                      // x = ij&63, z = ij>>6
        v = ((ij >> 6) << 12) | (plane << 6) | (ij & 63);
        n = v + 64;
    } else {                                     // z-faces: planes 7..55
        int r3 = r - 24576;
        int plane = 7 + ((r3 >> 12) << 3);
        int ij = r3 & 4095;                      // x = ij&63, y = ij>>6
        v = (plane << 12) | ((ij >> 6) << 6) | (ij & 63);
        n = v + 4096;
    }

    int lane = threadIdx.x & 63;

    int pa = LP[v], pb = LP[n];
    int la = LL[v], lb = LL[n];
    bool doP = (pa >= 0) & (pb >= 0);
    bool doL = (la >= 0) & (lb >= 0);

    // raw-pair dedupe (kills the chase for run-duplicates)
    int xpa = __shfl_up(pa, 1, 64), xpb = __shfl_up(pb, 1, 64);
    int xla = __shfl_up(la, 1, 64), xlb = __shfl_up(lb, 1, 64);
    if (lane && xpa == pa && xpb == pb) doP = false;
    if (lane && xla == la && xlb == lb) doL = false;

    int rp0 = -1, rp1 = -1, rl0 = -1, rl1 = -1;
    if (doP) {
        chase2(LP, pa, pb);
        rp0 = min(pa, pb); rp1 = max(pa, pb);
    }
    if (doL) {
        chase2(LL, la, lb);
        rl0 = min(la, lb); rl1 = max(la, lb);
    }

    // root-pair dedupe (different raw pairs may share final roots)
    int qp0 = __shfl_up(rp0, 1, 64), qp1 = __shfl_up(rp1, 1, 64);
    int ql0 = __shfl_up(rl0, 1, 64), ql1 = __shfl_up(rl1, 1, 64);
    bool dupP = lane && (qp0 == rp0) && (qp1 == rp1);
    bool dupL = lane && (ql0 == rl0) && (ql1 == rl1);

    if (rp0 >= 0 && rp0 != rp1 && !dupP) unite(LP, rp0, rp1);
    if (rl0 >= 0 && rl0 != rl1 && !dupL) unite(LL, rl0, rl1);
}

// ---------------------------------------------------------------------------
// 27-bit 3x3x3 mask connectivity via branch-free separable dilation.
// Bit index = z*9 + y*3 + x.
// ---------------------------------------------------------------------------
#define MX_L 0x6DB6DB6u   // result x in {1,2}
#define MX_R 0x36DB6DBu   // result x in {0,1}
#define MY_L 0x7E3F1F8u   // result y in {1,2}
#define MY_R 0x0FC7E3Fu   // result y in {0,1}
#define M27  0x7FFFFFFu

__device__ __forceinline__ unsigned dil26(unsigned m) {
    m |= ((m << 1) & MX_L) | ((m >> 1) & MX_R);
    m |= ((m << 3) & MY_L) | ((m >> 3) & MY_R);
    m |= ((m << 9) & M27)  | (m >> 9);
    return m;
}
__device__ __forceinline__ unsigned dil18(unsigned m) {
    unsigned ax = m | ((m << 1) & MX_L) | ((m >> 1) & MX_R);    // Dx
    unsigned ay = m | ((m << 3) & MY_L) | ((m >> 3) & MY_R);    // Dy
    unsigned dxy = ax | ((ax << 3) & MY_L) | ((ax >> 3) & MY_R);      // DyDx
    unsigned dxz = ax | ((ax << 9) & M27)  | (ax >> 9);               // DzDx
    unsigned dyz = ay | ((ay << 9) & M27)  | (ay >> 9);               // DzDy
    return dxy | dxz | dyz;   // all offsets with >=1 zero component
}

__device__ __forceinline__ bool single18(unsigned m) {
    if (!m) return false;
    unsigned c = m & (~m + 1u);
    for (;;) {
        unsigned n = dil18(c) & m;
        if (n == m) return true;
        if (n == c) return false;
        c = n;
    }
}
__device__ __forceinline__ bool single26(unsigned m) {
    if (!m) return false;
    unsigned c = m & (~m + 1u);
    for (;;) {
        unsigned n = dil26(c) & m;
        if (n == m) return true;
        if (n == c) return false;
        c = n;
    }
}

// ---------------------------------------------------------------------------
// Phase 3: non-simple maps + weighted BCE + mean. Region 8x8x8 per block
// (512 blocks, 2 voxels/thread), halo 10x10x10 per field.
// R11: wave-stepped batched chasing -- each loop round issues up to 8
// independent parent loads (one memory latency) and advances all 8 halo
// entries together; the common 0/1-hop case settles in ~2 rounds instead of
// 8 sequential dependent chases. Re-loading settled roots is idempotent.
// ---------------------------------------------------------------------------
#define HV 1000   // 10*10*10

__global__ void finalize_kernel(const float* __restrict__ pred,
                                const float* __restrict__ lab,
                                const int* __restrict__ LP,
                                const int* __restrict__ LL,
                                float* __restrict__ out) {
    __shared__ int sP[HV], sL[HV];
    __shared__ float s_part[4];
    int t = threadIdx.x;
    int b = blockIdx.x;                          // 8 x 8 x 8 regions
    int rx = b & 7, ry = (b >> 3) & 7, rz = b >> 6;
    int x0 = rx << 3, y0 = ry << 3, z0 = rz << 3;

    // batched halo load: all 8 independent loads issued together
    int pv[4], lv[4];
#pragma unroll
    for (int j = 0; j < 4; ++j) {
        int i = t + (j << 8);
        if (i < HV) {
            int hx = i % 10, rr = i / 10, hy = rr % 10, hz = rr / 10;
            int gx = x0 + hx - 1; gx = gx < 0 ? 0 : (gx > 63 ? 63 : gx);
            int gy = y0 + hy - 1; gy = gy < 0 ? 0 : (gy > 63 ? 63 : gy);
            int gz = z0 + hz - 1; gz = gz < 0 ? 0 : (gz > 63 ? 63 : gz);
            int gv = (gz << 12) | (gy << 6) | gx;
            pv[j] = LP[gv];
            lv[j] = LL[gv];
        } else {
            pv[j] = -1;
            lv[j] = -1;
        }
    }
    // wave-stepped chase: advance all entries one hop per round
    for (;;) {
        bool done = true;
#pragma unroll
        for (int j = 0; j < 4; ++j) {
            if (pv[j] >= 0) {
                int q = LP[pv[j]];
                if (q != pv[j]) { pv[j] = q; done = false; }
            }
            if (lv[j] >= 0) {
                int q = LL[lv[j]];
                if (q != lv[j]) { lv[j] = q; done = false; }
            }
        }
        if (done) break;
    }
#pragma unroll
    for (int j = 0; j < 4; ++j) {
        int i = t + (j << 8);
        if (i < HV) { sP[i] = pv[j]; sL[i] = lv[j]; }
    }
    __syncthreads();

    float acc = 0.0f;
#pragma unroll
    for (int j = 0; j < 2; ++j) {
        int l = t + (j << 8);                    // region 8x8x8: 512 voxels
        int lx = l & 7, ly = (l >> 3) & 7, lz = l >> 6;
        int x = x0 | lx, y = y0 | ly, z = z0 | lz;
        int v = (z << 12) | (y << 6) | x;
        int base = lz * 100 + ly * 10 + lx;      // (-1,-1,-1) corner

        bool nsP = false, nsL = false;
        {
            int c = sP[base + 111];              // center
            if (c >= 0) {
                unsigned m1 = 0, m2 = 0; int k = 0;
#pragma unroll
                for (int kz = 0; kz < 3; ++kz)
#pragma unroll
                    for (int ky = 0; ky < 3; ++ky)
#pragma unroll
                        for (int kx = 0; kx < 3; ++kx, ++k) {
                            int w = sP[base + kz * 100 + ky * 10 + kx];
                            m1 |= (unsigned)(w != c) << k;
                            m2 |= (unsigned)(w == c) << k;
                        }
                m2 &= ~(1u << 13);               // drop center
                nsP = !(single18(m1) && single26(m2));
            }
        }
        {
            int c = sL[base + 111];
            if (c >= 0) {
                unsigned m1 = 0, m2 = 0; int k = 0;
#pragma unroll
                for (int kz = 0; kz < 3; ++kz)
#pragma unroll
                    for (int ky = 0; ky < 3; ++ky)
#pragma unroll
                        for (int kx = 0; kx < 3; ++kx, ++k) {
                            int w = sL[base + kz * 100 + ky * 10 + kx];
                            m1 |= (unsigned)(w != c) << k;
                            m2 |= (unsigned)(w == c) << k;
                        }
                m2 &= ~(1u << 13);
                nsL = !(single18(m1) && single26(m2));
            }
        }

        float p = pred[v], lvf = lab[v];
        float cost = fmaxf(p, 0.0f) - p * lvf + log1pf(__expf(-fabsf(p)));
        acc += ((nsP || nsL) ? 5.0f : 1.0f) * cost;
    }

#pragma unroll
    for (int off = 32; off > 0; off >>= 1)
        acc += __shfl_down(acc, off, 64);
    if ((t & 63) == 0) s_part[t >> 6] = acc;
    __syncthreads();
    if (t == 0) {
        float s = s_part[0] + s_part[1] + s_part[2] + s_part[3];
        atomicAdd(out, s * (1.0f / (float)NVOX));
    }
}

extern "C" void kernel_launch(void* const* d_in, const int* in_sizes, int n_in,
                              void* d_out, int out_size, void* d_ws, size_t ws_size,
                              hipStream_t stream) {
    const float* pred = (const float*)d_in[0];   // 'prediction'
    const float* lab  = (const float*)d_in[1];   // 'label'
    float* out = (float*)d_out;

    int* LP = (int*)d_ws;          // NVOX ints
    int* LL = LP + NVOX;           // NVOX ints  (2 MiB total)

    hipLaunchKernelGGL(local_ccl, dim3(128, 2), dim3(256), 0, stream,
                       pred, lab, LP, LL, out);
    hipLaunchKernelGGL(boundary_link, dim3(EPF / 256), dim3(256), 0, stream,
                       LP, LL);
    hipLaunchKernelGGL(finalize_kernel, dim3(512), dim3(256), 0, stream,
                       pred, lab, LP, LL, out);
}